// Round 6
// baseline (909.790 us; speedup 1.0000x reference)
//
#include <hip/hip_runtime.h>

// GIN on MI355X. Round 6 = round 5 + ping-pong y buffers (fixes the in-place
// read/write race the fusion introduced: blocks gather neighbor rows of y
// while other blocks write the next layer's y — must be different buffers).

constexpr int N   = 100000;
constexpr int E   = 1600000;
constexpr int DIN = 128;
constexpr int H   = 64;
constexpr int OUT = 16;
constexpr int G   = 512;

constexpr int NB_NODES  = (N + 255) / 256;   // 391
constexpr int NB_EDGES  = (E + 255) / 256;   // 6250
constexpr int NB_TILE64 = (N + 63) / 64;     // 1563 (64-node tiles)

__device__ __forceinline__ float bf2f(unsigned short u) {
  union { unsigned int i; float f; } v;
  v.i = ((unsigned int)u) << 16;
  return v.f;
}
__device__ __forceinline__ unsigned int f2bf(float f) {
  union { float f; unsigned int i; } v;
  v.f = f;
  unsigned int r = v.i + 0x7fff + ((v.i >> 16) & 1);  // RNE
  return r >> 16;
}

// ---------------- CSR build ----------------
__global__ void k_hist(const int* __restrict__ dst, int* __restrict__ deg) {
  int e = blockIdx.x * 256 + threadIdx.x;
  if (e < E) atomicAdd(&deg[dst[e]], 1);
}

__global__ void k_scan_block(const int* __restrict__ deg, int* __restrict__ rowptr,
                             int* __restrict__ bsums) {
  __shared__ int s[256];
  int i = blockIdx.x * 256 + threadIdx.x;
  int v = (i < N) ? deg[i] : 0;
  s[threadIdx.x] = v;
  __syncthreads();
  for (int off = 1; off < 256; off <<= 1) {
    int t = 0;
    if ((int)threadIdx.x >= off) t = s[threadIdx.x - off];
    __syncthreads();
    if ((int)threadIdx.x >= off) s[threadIdx.x] += t;
    __syncthreads();
  }
  if (i < N) rowptr[i] = s[threadIdx.x] - v;
  if (threadIdx.x == 255) bsums[blockIdx.x] = s[255];
}

__global__ void k_scan_sums(int* __restrict__ bsums, int nb) {
  __shared__ int s[512];
  int t = threadIdx.x;
  int v = (t < nb) ? bsums[t] : 0;
  s[t] = v;
  __syncthreads();
  for (int off = 1; off < 512; off <<= 1) {
    int u = 0;
    if (t >= off) u = s[t - off];
    __syncthreads();
    if (t >= off) s[t] += u;
    __syncthreads();
  }
  if (t < nb) bsums[t] = s[t] - v;
}

__global__ void k_scan_add(int* __restrict__ rowptr, const int* __restrict__ bsums,
                           int* __restrict__ cursor) {
  int i = blockIdx.x * 256 + threadIdx.x;
  if (i < N) {
    int v = rowptr[i] + bsums[blockIdx.x];
    rowptr[i] = v;
    cursor[i] = v;
  }
  if (i == 0) rowptr[N] = E;
}

__global__ void k_fill(const int* __restrict__ src, const int* __restrict__ dst,
                       int* __restrict__ cursor, int* __restrict__ col) {
  int e = blockIdx.x * 256 + threadIdx.x;
  if (e < E) {
    int s = src[e];
    int p = atomicAdd(&cursor[dst[e]], 1);
    __builtin_nontemporal_store(s, &col[p]);
  }
}

// ---- y0 = x @ w1_0 (N x 128 -> N x 64, bf16 out). 64-node tile per block. ----
__global__ __launch_bounds__(256, 4) void k_gemm_in(const float* __restrict__ x,
                                                    const float* __restrict__ w1,
                                                    unsigned short* __restrict__ y) {
  __shared__ float sx[64 * 129];
  int t = threadIdx.x;
  int nb = blockIdx.x * 64;
  int rows = min(64, N - nb);
#pragma unroll
  for (int it = 0; it < 8; ++it) {
    int idx4 = it * 256 + t;  // float4 index, 0..2047
    int r = idx4 >> 5, d4 = idx4 & 31;
    if (r < rows) {
      float4 v = ((const float4*)(x + (size_t)(nb + r) * DIN))[d4];
      float* dl = &sx[r * 129 + d4 * 4];
      dl[0] = v.x; dl[1] = v.y; dl[2] = v.z; dl[3] = v.w;
    }
  }
  __syncthreads();
  int l = t & 63;
  int jg = __builtin_amdgcn_readfirstlane(t >> 6);
  float acc[16];
#pragma unroll
  for (int j = 0; j < 16; ++j) acc[j] = 0.f;
#pragma unroll 4
  for (int d = 0; d < DIN; ++d) {
    float v = sx[l * 129 + d];
    const float* wr = w1 + d * H + jg * 16;
#pragma unroll
    for (int j = 0; j < 16; ++j) acc[j] += v * wr[j];
  }
  __syncthreads();
  unsigned int* so = (unsigned int*)sx;
#pragma unroll
  for (int k = 0; k < 8; ++k)
    so[l * 33 + jg * 8 + k] = f2bf(acc[2 * k]) | (f2bf(acc[2 * k + 1]) << 16);
  __syncthreads();
  unsigned int* yo = (unsigned int*)y;
#pragma unroll
  for (int it = 0; it < 8; ++it) {
    int m = it * 256 + t;
    int r = m >> 5, k = m & 31;
    if (r < rows) yo[(size_t)(nb + r) * 32 + k] = so[r * 33 + k];
  }
}

// Aggregate one node (wave-uniform `node`) into per-lane float; 8 outstanding.
__device__ __forceinline__ float agg_node(const unsigned short* __restrict__ y,
                                          const int* __restrict__ rowptr,
                                          const int* __restrict__ col,
                                          int node, int lane) {
  int r0 = rowptr[node], r1 = rowptr[node + 1];
  float a0 = bf2f(y[(size_t)node * H + lane]);
  float a1 = 0.f, a2 = 0.f, a3 = 0.f, a4 = 0.f, a5 = 0.f, a6 = 0.f, a7 = 0.f;
  int deg = r1 - r0;
  int kend = r0 + (deg & ~7);
  for (int k = r0; k < kend; k += 8) {
    int c = (lane < 8) ? col[k + lane] : 0;
    int c0 = __shfl(c, 0), c1 = __shfl(c, 1), c2 = __shfl(c, 2), c3 = __shfl(c, 3);
    int c4 = __shfl(c, 4), c5 = __shfl(c, 5), c6 = __shfl(c, 6), c7 = __shfl(c, 7);
    a0 += bf2f(y[(size_t)c0 * H + lane]);
    a1 += bf2f(y[(size_t)c1 * H + lane]);
    a2 += bf2f(y[(size_t)c2 * H + lane]);
    a3 += bf2f(y[(size_t)c3 * H + lane]);
    a4 += bf2f(y[(size_t)c4 * H + lane]);
    a5 += bf2f(y[(size_t)c5 * H + lane]);
    a6 += bf2f(y[(size_t)c6 * H + lane]);
    a7 += bf2f(y[(size_t)c7 * H + lane]);
  }
  int k = kend;
  if (deg & 4) {
    int c = (lane < 4) ? col[k + lane] : 0;
    int c0 = __shfl(c, 0), c1 = __shfl(c, 1), c2 = __shfl(c, 2), c3 = __shfl(c, 3);
    a0 += bf2f(y[(size_t)c0 * H + lane]);
    a1 += bf2f(y[(size_t)c1 * H + lane]);
    a2 += bf2f(y[(size_t)c2 * H + lane]);
    a3 += bf2f(y[(size_t)c3 * H + lane]);
    k += 4;
  }
  if (deg & 2) {
    int c = (lane < 2) ? col[k + lane] : 0;
    int c0 = __shfl(c, 0), c1 = __shfl(c, 1);
    a4 += bf2f(y[(size_t)c0 * H + lane]);
    a5 += bf2f(y[(size_t)c1 * H + lane]);
    k += 2;
  }
  if (deg & 1) {
    int c0 = col[k];
    a6 += bf2f(y[(size_t)c0 * H + lane]);
  }
  return ((a0 + a1) + (a2 + a3)) + ((a4 + a5) + (a6 + a7));
}

// ---- fused: agg(+b1,relu) -> LDS tile -> GEMM2(+b2,relu) -> GEMM1next -> bf16 y ----
// yin and yout MUST be different buffers (cross-block race otherwise).
__global__ __launch_bounds__(256, 4) void k_agg_mlp(const unsigned short* __restrict__ yin,
                                                    const int* __restrict__ rowptr,
                                                    const int* __restrict__ col,
                                                    const float* __restrict__ b1,
                                                    const float* __restrict__ w2,
                                                    const float* __restrict__ b2,
                                                    const float* __restrict__ w1n,
                                                    unsigned short* __restrict__ yout) {
  __shared__ float sa[64 * 65];
  __shared__ float sb[64 * 65];
  int t = threadIdx.x;
  int nb = blockIdx.x * 64;
  int rows = min(64, N - nb);
  int l = t & 63;
  int q = t >> 6;
  float bias1 = b1[l];
  for (int r = q * 16; r < q * 16 + 16; ++r) {
    if (r < rows) {
      float v = agg_node(yin, rowptr, col, nb + r, l) + bias1;
      sa[r * 65 + l] = fmaxf(v, 0.f);
    }
  }
  __syncthreads();
  int jg = __builtin_amdgcn_readfirstlane(q);
  float h[16];
#pragma unroll
  for (int j = 0; j < 16; ++j) h[j] = b2[jg * 16 + j];
#pragma unroll 4
  for (int d = 0; d < H; ++d) {
    float v = sa[l * 65 + d];
    const float* wr = w2 + d * H + jg * 16;
#pragma unroll
    for (int j = 0; j < 16; ++j) h[j] += v * wr[j];
  }
#pragma unroll
  for (int j = 0; j < 16; ++j) sb[l * 65 + jg * 16 + j] = fmaxf(h[j], 0.f);
  __syncthreads();
  float a[16];
#pragma unroll
  for (int j = 0; j < 16; ++j) a[j] = 0.f;
#pragma unroll 4
  for (int d = 0; d < H; ++d) {
    float v = sb[l * 65 + d];
    const float* wr = w1n + d * H + jg * 16;
#pragma unroll
    for (int j = 0; j < 16; ++j) a[j] += v * wr[j];
  }
  unsigned int* so = (unsigned int*)sa;  // sa reads finished before 2nd barrier
#pragma unroll
  for (int k = 0; k < 8; ++k)
    so[l * 33 + jg * 8 + k] = f2bf(a[2 * k]) | (f2bf(a[2 * k + 1]) << 16);
  __syncthreads();
  unsigned int* yo = (unsigned int*)yout;
#pragma unroll
  for (int it = 0; it < 8; ++it) {
    int m = it * 256 + t;
    int r = m >> 5, k = m & 31;
    if (r < rows) yo[(size_t)(nb + r) * 32 + k] = so[r * 33 + k];
  }
}

// ---- layer 4: agg -> GEMM2(+b2,relu) -> segment-reduce pool into g ----
__global__ __launch_bounds__(256, 4) void k_agg_last_pool(const unsigned short* __restrict__ yin,
                                                          const int* __restrict__ rowptr,
                                                          const int* __restrict__ col,
                                                          const float* __restrict__ b1,
                                                          const float* __restrict__ w2,
                                                          const float* __restrict__ b2,
                                                          const int* __restrict__ batch,
                                                          float* __restrict__ g) {
  __shared__ float sa[64 * 65];
  __shared__ float sb[64 * 65];
  __shared__ int sbatch[64];
  int t = threadIdx.x;
  int nb = blockIdx.x * 64;
  int rows = min(64, N - nb);
  int l = t & 63;
  int q = t >> 6;
  if (t < 64) sbatch[t] = batch[min(nb + t, N - 1)];
  float bias1 = b1[l];
  for (int r = q * 16; r < q * 16 + 16; ++r) {
    if (r < rows) {
      float v = agg_node(yin, rowptr, col, nb + r, l) + bias1;
      sa[r * 65 + l] = fmaxf(v, 0.f);
    }
  }
  __syncthreads();
  int jg = __builtin_amdgcn_readfirstlane(q);
  float h[16];
#pragma unroll
  for (int j = 0; j < 16; ++j) h[j] = b2[jg * 16 + j];
#pragma unroll 4
  for (int d = 0; d < H; ++d) {
    float v = sa[l * 65 + d];
    const float* wr = w2 + d * H + jg * 16;
#pragma unroll
    for (int j = 0; j < 16; ++j) h[j] += v * wr[j];
  }
#pragma unroll
  for (int j = 0; j < 16; ++j) sb[l * 65 + jg * 16 + j] = fmaxf(h[j], 0.f);
  __syncthreads();
  int d = t & 63;
  int r0 = q * 16;
  int bprev = sbatch[r0];
  float acc = 0.f;
#pragma unroll 4
  for (int r = 0; r < 16; ++r) {
    int row = r0 + r;
    if (row >= rows) break;
    int b = sbatch[row];
    if (b != bprev) {
      __hip_atomic_fetch_add(&g[(size_t)bprev * H + d], acc,
                             __ATOMIC_RELAXED, __HIP_MEMORY_SCOPE_AGENT);
      acc = 0.f;
      bprev = b;
    }
    acc += sb[row * 65 + d];
  }
  if (r0 < rows)
    __hip_atomic_fetch_add(&g[(size_t)bprev * H + d], acc,
                           __ATOMIC_RELAXED, __HIP_MEMORY_SCOPE_AGENT);
}

// out[n] = relu(g[n] @ mw1 + mb1) @ mw2 + mb2
__global__ void k_readout(const float* __restrict__ g, const float* __restrict__ mw1,
                          const float* __restrict__ mb1, const float* __restrict__ mw2,
                          const float* __restrict__ mb2, float* __restrict__ out) {
  int n = blockIdx.x * 64 + threadIdx.x;
  if (n >= G) return;
  float acc[H];
#pragma unroll
  for (int j = 0; j < H; ++j) acc[j] = mb1[j];
  const float* gr = g + (size_t)n * H;
  for (int d = 0; d < H; ++d) {
    float gd = gr[d];
    const float* wr = mw1 + d * H;
#pragma unroll
    for (int j = 0; j < H; ++j) acc[j] += gd * wr[j];
  }
#pragma unroll
  for (int j = 0; j < H; ++j) acc[j] = fmaxf(acc[j], 0.f);
  float o[OUT];
#pragma unroll
  for (int tt = 0; tt < OUT; ++tt) o[tt] = mb2[tt];
  for (int d = 0; d < H; ++d) {
    float hd = acc[d];
    const float* wr = mw2 + d * OUT;
#pragma unroll
    for (int tt = 0; tt < OUT; ++tt) o[tt] += hd * wr[tt];
  }
#pragma unroll
  for (int tt = 0; tt < OUT; ++tt) out[(size_t)n * OUT + tt] = o[tt];
}

extern "C" void kernel_launch(void* const* d_in, const int* in_sizes, int n_in,
                              void* d_out, int out_size, void* d_ws, size_t ws_size,
                              hipStream_t stream) {
  const float* x     = (const float*)d_in[0];
  const int*   ei    = (const int*)d_in[1];
  const int*   batch = (const int*)d_in[2];
  const float* w1_0  = (const float*)d_in[3];
  const float* b1_0  = (const float*)d_in[4];
  const float* w2_0  = (const float*)d_in[5];
  const float* b2_0  = (const float*)d_in[6];
  const float* w1_r  = (const float*)d_in[7];
  const float* b1_r  = (const float*)d_in[8];
  const float* w2_r  = (const float*)d_in[9];
  const float* b2_r  = (const float*)d_in[10];
  const float* mw1   = (const float*)d_in[11];
  const float* mb1   = (const float*)d_in[12];
  const float* mw2   = (const float*)d_in[13];
  const float* mb2   = (const float*)d_in[14];
  float* out = (float*)d_out;

  const int* src = ei;
  const int* dst = ei + E;

  char* ws = (char*)d_ws;
  size_t off = 0;
  auto alloc = [&](size_t bytes) -> void* {
    void* p = ws + off;
    off = (off + bytes + 255) & ~(size_t)255;
    return p;
  };
  unsigned short* ybufA = (unsigned short*)alloc((size_t)N * H * 2);
  unsigned short* ybufB = (unsigned short*)alloc((size_t)N * H * 2);
  int* rowptr = (int*)alloc((size_t)(N + 1) * 4);
  int* cursor = (int*)alloc((size_t)N * 4);
  int* col    = (int*)alloc((size_t)E * 4);
  int* bsums  = (int*)alloc(512 * 4);
  float* gbuf = (float*)alloc((size_t)G * H * 4);

  // ---- CSR build ----
  hipMemsetAsync(cursor, 0, (size_t)N * 4, stream);
  k_hist<<<NB_EDGES, 256, 0, stream>>>(dst, cursor);
  k_scan_block<<<NB_NODES, 256, 0, stream>>>(cursor, rowptr, bsums);
  k_scan_sums<<<1, 512, 0, stream>>>(bsums, NB_NODES);
  k_scan_add<<<NB_NODES, 256, 0, stream>>>(rowptr, bsums, cursor);
  k_fill<<<NB_EDGES, 256, 0, stream>>>(src, dst, cursor, col);

  hipMemsetAsync(gbuf, 0, (size_t)G * H * 4, stream);

  // ---- layer 0 input GEMM ----
  k_gemm_in<<<NB_TILE64, 256, 0, stream>>>(x, w1_0, ybufA);

  // ---- layers 0..3 fused agg+MLP, ping-pong A<->B ----
  k_agg_mlp<<<NB_TILE64, 256, 0, stream>>>(ybufA, rowptr, col, b1_0, w2_0, b2_0,
                                           w1_r, ybufB);
  k_agg_mlp<<<NB_TILE64, 256, 0, stream>>>(ybufB, rowptr, col, b1_r + 0 * H,
                                           w2_r + 0 * H * H, b2_r + 0 * H,
                                           w1_r + 1 * H * H, ybufA);
  k_agg_mlp<<<NB_TILE64, 256, 0, stream>>>(ybufA, rowptr, col, b1_r + 1 * H,
                                           w2_r + 1 * H * H, b2_r + 1 * H,
                                           w1_r + 2 * H * H, ybufB);
  k_agg_mlp<<<NB_TILE64, 256, 0, stream>>>(ybufB, rowptr, col, b1_r + 2 * H,
                                           w2_r + 2 * H * H, b2_r + 2 * H,
                                           w1_r + 3 * H * H, ybufA);

  // ---- layer 4: agg + GEMM2 + pool ----
  k_agg_last_pool<<<NB_TILE64, 256, 0, stream>>>(ybufA, rowptr, col, b1_r + 3 * H,
                                                 w2_r + 3 * H * H, b2_r + 3 * H,
                                                 batch, gbuf);

  // ---- readout ----
  k_readout<<<8, 64, 0, stream>>>(gbuf, mw1, mb1, mw2, mb2, out);
}

// Round 7
// 784.431 us; speedup vs baseline: 1.1598x; 1.1598x over previous
//
#include <hip/hip_runtime.h>

// GIN on MI355X. Round 7: revert to round-4 separated agg/MLP structure
// (fusion regressed: agg needs max TLP, not block-serialized nodes), plus:
//  - k_gemm_in fused into k_fill's launch (independent work, block-range split)
//  - u buffer stored bf16 (halves agg write + fused read traffic)
//  - agg col-index broadcast via same-address loads instead of shfl/bpermute

constexpr int N   = 100000;
constexpr int E   = 1600000;
constexpr int DIN = 128;
constexpr int H   = 64;
constexpr int OUT = 16;
constexpr int G   = 512;

constexpr int NB_NODES    = (N + 255) / 256;       // 391
constexpr int NB_EDGES    = (E + 255) / 256;       // 6250
constexpr int NB_WAVENODE = (N * 64 + 255) / 256;  // 25000 (wave per node)
constexpr int NB_TILE64   = (N + 63) / 64;         // 1563 (64-node tiles)

__device__ __forceinline__ float bf2f(unsigned short u) {
  union { unsigned int i; float f; } v;
  v.i = ((unsigned int)u) << 16;
  return v.f;
}
__device__ __forceinline__ unsigned int f2bf(float f) {
  union { float f; unsigned int i; } v;
  v.f = f;
  unsigned int r = v.i + 0x7fff + ((v.i >> 16) & 1);  // RNE
  return r >> 16;
}

// ---------------- CSR build ----------------
__global__ void k_hist(const int* __restrict__ dst, int* __restrict__ deg) {
  int e = blockIdx.x * 256 + threadIdx.x;
  if (e < E) atomicAdd(&deg[dst[e]], 1);
}

__global__ void k_scan_block(const int* __restrict__ deg, int* __restrict__ rowptr,
                             int* __restrict__ bsums) {
  __shared__ int s[256];
  int i = blockIdx.x * 256 + threadIdx.x;
  int v = (i < N) ? deg[i] : 0;
  s[threadIdx.x] = v;
  __syncthreads();
  for (int off = 1; off < 256; off <<= 1) {
    int t = 0;
    if ((int)threadIdx.x >= off) t = s[threadIdx.x - off];
    __syncthreads();
    if ((int)threadIdx.x >= off) s[threadIdx.x] += t;
    __syncthreads();
  }
  if (i < N) rowptr[i] = s[threadIdx.x] - v;
  if (threadIdx.x == 255) bsums[blockIdx.x] = s[255];
}

__global__ void k_scan_sums(int* __restrict__ bsums, int nb) {
  __shared__ int s[512];
  int t = threadIdx.x;
  int v = (t < nb) ? bsums[t] : 0;
  s[t] = v;
  __syncthreads();
  for (int off = 1; off < 512; off <<= 1) {
    int u = 0;
    if (t >= off) u = s[t - off];
    __syncthreads();
    if (t >= off) s[t] += u;
    __syncthreads();
  }
  if (t < nb) bsums[t] = s[t] - v;
}

__global__ void k_scan_add(int* __restrict__ rowptr, const int* __restrict__ bsums,
                           int* __restrict__ cursor) {
  int i = blockIdx.x * 256 + threadIdx.x;
  if (i < N) {
    int v = rowptr[i] + bsums[blockIdx.x];
    rowptr[i] = v;
    cursor[i] = v;
  }
  if (i == 0) rowptr[N] = E;
}

// ---- fused launch: blocks [0,NB_TILE64) do y0 = x@w1_0 (bf16 out);
//      blocks [NB_TILE64, NB_TILE64+NB_EDGES) do the CSR col-fill.
//      Independent work overlapped in one dispatch (same-stream kernels
//      cannot overlap otherwise). ----
__global__ __launch_bounds__(256, 4) void k_fill_gemm(const int* __restrict__ src,
                                                      const int* __restrict__ dst,
                                                      int* __restrict__ cursor,
                                                      int* __restrict__ col,
                                                      const float* __restrict__ x,
                                                      const float* __restrict__ w1,
                                                      unsigned short* __restrict__ y) {
  __shared__ float sx[64 * 129];
  int t = threadIdx.x;
  if (blockIdx.x >= NB_TILE64) {
    // ---- fill path ----
    int e = (blockIdx.x - NB_TILE64) * 256 + t;
    if (e < E) {
      int s = src[e];
      int p = atomicAdd(&cursor[dst[e]], 1);
      __builtin_nontemporal_store(s, &col[p]);
    }
    return;
  }
  // ---- gemm path ----
  int nb = blockIdx.x * 64;
  int rows = min(64, N - nb);
#pragma unroll
  for (int it = 0; it < 8; ++it) {
    int idx4 = it * 256 + t;  // float4 index, 0..2047
    int r = idx4 >> 5, d4 = idx4 & 31;
    if (r < rows) {
      float4 v = ((const float4*)(x + (size_t)(nb + r) * DIN))[d4];
      float* dl = &sx[r * 129 + d4 * 4];
      dl[0] = v.x; dl[1] = v.y; dl[2] = v.z; dl[3] = v.w;
    }
  }
  __syncthreads();
  int l = t & 63;
  int jg = __builtin_amdgcn_readfirstlane(t >> 6);
  float acc[16];
#pragma unroll
  for (int j = 0; j < 16; ++j) acc[j] = 0.f;
#pragma unroll 4
  for (int d = 0; d < DIN; ++d) {
    float v = sx[l * 129 + d];
    const float* wr = w1 + d * H + jg * 16;
#pragma unroll
    for (int j = 0; j < 16; ++j) acc[j] += v * wr[j];
  }
  __syncthreads();
  unsigned int* so = (unsigned int*)sx;
#pragma unroll
  for (int k = 0; k < 8; ++k)
    so[l * 33 + jg * 8 + k] = f2bf(acc[2 * k]) | (f2bf(acc[2 * k + 1]) << 16);
  __syncthreads();
  unsigned int* yo = (unsigned int*)y;
#pragma unroll
  for (int it = 0; it < 8; ++it) {
    int m = it * 256 + t;
    int r = m >> 5, k = m & 31;
    if (r < rows) yo[(size_t)(nb + r) * 32 + k] = so[r * 33 + k];
  }
}

// ---- u = bf16(relu(y + A*y + b1)); wave/node, lane/feat, 8 outstanding.
//      col indices broadcast by same-address loads (no shfl). ----
__global__ void k_agg(const unsigned short* __restrict__ y, const int* __restrict__ rowptr,
                      const int* __restrict__ col, const float* __restrict__ b1,
                      unsigned short* __restrict__ u) {
  int w = (blockIdx.x * 256 + threadIdx.x) >> 6;
  int lane = threadIdx.x & 63;
  if (w >= N) return;
  int r0 = rowptr[w], r1 = rowptr[w + 1];
  float a0 = bf2f(y[(size_t)w * H + lane]);
  float a1 = 0.f, a2 = 0.f, a3 = 0.f, a4 = 0.f, a5 = 0.f, a6 = 0.f, a7 = 0.f;
  int deg = r1 - r0;
  int kend = r0 + (deg & ~7);
  for (int k = r0; k < kend; k += 8) {
    int c0 = col[k],     c1 = col[k + 1], c2 = col[k + 2], c3 = col[k + 3];
    int c4 = col[k + 4], c5 = col[k + 5], c6 = col[k + 6], c7 = col[k + 7];
    a0 += bf2f(y[(size_t)c0 * H + lane]);
    a1 += bf2f(y[(size_t)c1 * H + lane]);
    a2 += bf2f(y[(size_t)c2 * H + lane]);
    a3 += bf2f(y[(size_t)c3 * H + lane]);
    a4 += bf2f(y[(size_t)c4 * H + lane]);
    a5 += bf2f(y[(size_t)c5 * H + lane]);
    a6 += bf2f(y[(size_t)c6 * H + lane]);
    a7 += bf2f(y[(size_t)c7 * H + lane]);
  }
  int k = kend;
  if (deg & 4) {
    int c0 = col[k], c1 = col[k + 1], c2 = col[k + 2], c3 = col[k + 3];
    a0 += bf2f(y[(size_t)c0 * H + lane]);
    a1 += bf2f(y[(size_t)c1 * H + lane]);
    a2 += bf2f(y[(size_t)c2 * H + lane]);
    a3 += bf2f(y[(size_t)c3 * H + lane]);
    k += 4;
  }
  if (deg & 2) {
    int c0 = col[k], c1 = col[k + 1];
    a4 += bf2f(y[(size_t)c0 * H + lane]);
    a5 += bf2f(y[(size_t)c1 * H + lane]);
    k += 2;
  }
  if (deg & 1) {
    int c0 = col[k];
    a6 += bf2f(y[(size_t)c0 * H + lane]);
  }
  float r = ((a0 + a1) + (a2 + a3)) + ((a4 + a5) + (a6 + a7)) + b1[lane];
  u[(size_t)w * H + lane] = (unsigned short)f2bf(fmaxf(r, 0.f));
}

// ---- y = (relu(u @ w2 + b2)) @ w1next, bf16 in (u) and out (y). 64-node tile.
//      Writing y in place is safe here: this kernel never reads y. ----
__global__ __launch_bounds__(256, 4) void k_fused(const unsigned short* __restrict__ u,
                                                  const float* __restrict__ w2,
                                                  const float* __restrict__ b2,
                                                  const float* __restrict__ w1n,
                                                  unsigned short* __restrict__ yout) {
  __shared__ float sa[64 * 65];
  __shared__ float sb[64 * 65];
  int t = threadIdx.x;
  int nb = blockIdx.x * 64;
  int rows = min(64, N - nb);
  const unsigned int* u32 = (const unsigned int*)u;
#pragma unroll
  for (int it = 0; it < 8; ++it) {
    int m = it * 256 + t;  // uint index, 0..2047 (32 per row)
    int r = m >> 5, c = m & 31;
    if (r < rows) {
      unsigned int v = u32[(size_t)(nb + r) * 32 + c];
      sa[r * 65 + c * 2]     = bf2f((unsigned short)(v & 0xffff));
      sa[r * 65 + c * 2 + 1] = bf2f((unsigned short)(v >> 16));
    }
  }
  __syncthreads();
  int l = t & 63;
  int jg = __builtin_amdgcn_readfirstlane(t >> 6);
  float h[16];
#pragma unroll
  for (int j = 0; j < 16; ++j) h[j] = b2[jg * 16 + j];
#pragma unroll 4
  for (int d = 0; d < H; ++d) {
    float v = sa[l * 65 + d];
    const float* wr = w2 + d * H + jg * 16;
#pragma unroll
    for (int j = 0; j < 16; ++j) h[j] += v * wr[j];
  }
#pragma unroll
  for (int j = 0; j < 16; ++j) sb[l * 65 + jg * 16 + j] = fmaxf(h[j], 0.f);
  __syncthreads();
  float a[16];
#pragma unroll
  for (int j = 0; j < 16; ++j) a[j] = 0.f;
#pragma unroll 4
  for (int d = 0; d < H; ++d) {
    float v = sb[l * 65 + d];
    const float* wr = w1n + d * H + jg * 16;
#pragma unroll
    for (int j = 0; j < 16; ++j) a[j] += v * wr[j];
  }
  unsigned int* so = (unsigned int*)sa;  // sa reads finished before 2nd barrier
#pragma unroll
  for (int k = 0; k < 8; ++k)
    so[l * 33 + jg * 8 + k] = f2bf(a[2 * k]) | (f2bf(a[2 * k + 1]) << 16);
  __syncthreads();
  unsigned int* yo = (unsigned int*)yout;
#pragma unroll
  for (int it = 0; it < 8; ++it) {
    int m = it * 256 + t;
    int r = m >> 5, k = m & 31;
    if (r < rows) yo[(size_t)(nb + r) * 32 + k] = so[r * 33 + k];
  }
}

// ---- layer 4: h5 = relu(u @ w2 + b2) (bf16 u in) + segment-reduce pool ----
__global__ __launch_bounds__(256, 4) void k_last_pool(const unsigned short* __restrict__ u,
                                                      const float* __restrict__ w2,
                                                      const float* __restrict__ b2,
                                                      const int* __restrict__ batch,
                                                      float* __restrict__ g) {
  __shared__ float sa[64 * 65];
  __shared__ float sb[64 * 65];
  __shared__ int sbatch[64];
  int t = threadIdx.x;
  int nb = blockIdx.x * 64;
  int rows = min(64, N - nb);
  const unsigned int* u32 = (const unsigned int*)u;
#pragma unroll
  for (int it = 0; it < 8; ++it) {
    int m = it * 256 + t;
    int r = m >> 5, c = m & 31;
    if (r < rows) {
      unsigned int v = u32[(size_t)(nb + r) * 32 + c];
      sa[r * 65 + c * 2]     = bf2f((unsigned short)(v & 0xffff));
      sa[r * 65 + c * 2 + 1] = bf2f((unsigned short)(v >> 16));
    }
  }
  if (t < 64) sbatch[t] = batch[min(nb + t, N - 1)];
  __syncthreads();
  int l = t & 63;
  int jg = __builtin_amdgcn_readfirstlane(t >> 6);
  float h[16];
#pragma unroll
  for (int j = 0; j < 16; ++j) h[j] = b2[jg * 16 + j];
#pragma unroll 4
  for (int d = 0; d < H; ++d) {
    float v = sa[l * 65 + d];
    const float* wr = w2 + d * H + jg * 16;
#pragma unroll
    for (int j = 0; j < 16; ++j) h[j] += v * wr[j];
  }
#pragma unroll
  for (int j = 0; j < 16; ++j) sb[l * 65 + jg * 16 + j] = fmaxf(h[j], 0.f);
  __syncthreads();
  // segment-reduce 16 rows per thread along sorted batch; one atomic per run
  int d = t & 63;
  int q = t >> 6;
  int r0 = q * 16;
  int bprev = sbatch[r0];
  float acc = 0.f;
#pragma unroll 4
  for (int r = 0; r < 16; ++r) {
    int row = r0 + r;
    if (row >= rows) break;
    int b = sbatch[row];
    if (b != bprev) {
      __hip_atomic_fetch_add(&g[(size_t)bprev * H + d], acc,
                             __ATOMIC_RELAXED, __HIP_MEMORY_SCOPE_AGENT);
      acc = 0.f;
      bprev = b;
    }
    acc += sb[row * 65 + d];
  }
  if (r0 < rows)
    __hip_atomic_fetch_add(&g[(size_t)bprev * H + d], acc,
                           __ATOMIC_RELAXED, __HIP_MEMORY_SCOPE_AGENT);
}

// out[n] = relu(g[n] @ mw1 + mb1) @ mw2 + mb2
__global__ void k_readout(const float* __restrict__ g, const float* __restrict__ mw1,
                          const float* __restrict__ mb1, const float* __restrict__ mw2,
                          const float* __restrict__ mb2, float* __restrict__ out) {
  int n = blockIdx.x * 64 + threadIdx.x;
  if (n >= G) return;
  float acc[H];
#pragma unroll
  for (int j = 0; j < H; ++j) acc[j] = mb1[j];
  const float* gr = g + (size_t)n * H;
  for (int d = 0; d < H; ++d) {
    float gd = gr[d];
    const float* wr = mw1 + d * H;
#pragma unroll
    for (int j = 0; j < H; ++j) acc[j] += gd * wr[j];
  }
#pragma unroll
  for (int j = 0; j < H; ++j) acc[j] = fmaxf(acc[j], 0.f);
  float o[OUT];
#pragma unroll
  for (int tt = 0; tt < OUT; ++tt) o[tt] = mb2[tt];
  for (int d = 0; d < H; ++d) {
    float hd = acc[d];
    const float* wr = mw2 + d * OUT;
#pragma unroll
    for (int tt = 0; tt < OUT; ++tt) o[tt] += hd * wr[tt];
  }
#pragma unroll
  for (int tt = 0; tt < OUT; ++tt) out[(size_t)n * OUT + tt] = o[tt];
}

extern "C" void kernel_launch(void* const* d_in, const int* in_sizes, int n_in,
                              void* d_out, int out_size, void* d_ws, size_t ws_size,
                              hipStream_t stream) {
  const float* x     = (const float*)d_in[0];
  const int*   ei    = (const int*)d_in[1];
  const int*   batch = (const int*)d_in[2];
  const float* w1_0  = (const float*)d_in[3];
  const float* b1_0  = (const float*)d_in[4];
  const float* w2_0  = (const float*)d_in[5];
  const float* b2_0  = (const float*)d_in[6];
  const float* w1_r  = (const float*)d_in[7];
  const float* b1_r  = (const float*)d_in[8];
  const float* w2_r  = (const float*)d_in[9];
  const float* b2_r  = (const float*)d_in[10];
  const float* mw1   = (const float*)d_in[11];
  const float* mb1   = (const float*)d_in[12];
  const float* mw2   = (const float*)d_in[13];
  const float* mb2   = (const float*)d_in[14];
  float* out = (float*)d_out;

  const int* src = ei;
  const int* dst = ei + E;

  char* ws = (char*)d_ws;
  size_t off = 0;
  auto alloc = [&](size_t bytes) -> void* {
    void* p = ws + off;
    off = (off + bytes + 255) & ~(size_t)255;
    return p;
  };
  unsigned short* ybuf = (unsigned short*)alloc((size_t)N * H * 2);  // y (bf16)
  unsigned short* ubuf = (unsigned short*)alloc((size_t)N * H * 2);  // u (bf16)
  int* rowptr = (int*)alloc((size_t)(N + 1) * 4);
  int* cursor = (int*)alloc((size_t)N * 4);
  int* col    = (int*)alloc((size_t)E * 4);
  int* bsums  = (int*)alloc(512 * 4);
  float* gbuf = (float*)alloc((size_t)G * H * 4);

  // ---- CSR build (hist -> scan), then fill overlapped with input GEMM ----
  hipMemsetAsync(cursor, 0, (size_t)N * 4, stream);
  hipMemsetAsync(gbuf, 0, (size_t)G * H * 4, stream);
  k_hist<<<NB_EDGES, 256, 0, stream>>>(dst, cursor);
  k_scan_block<<<NB_NODES, 256, 0, stream>>>(cursor, rowptr, bsums);
  k_scan_sums<<<1, 512, 0, stream>>>(bsums, NB_NODES);
  k_scan_add<<<NB_NODES, 256, 0, stream>>>(rowptr, bsums, cursor);

  k_fill_gemm<<<NB_TILE64 + NB_EDGES, 256, 0, stream>>>(src, dst, cursor, col,
                                                        x, w1_0, ybuf);

  // ---- layers 0..3: agg -> fused MLP (y updated in place by k_fused only) ----
  k_agg<<<NB_WAVENODE, 256, 0, stream>>>(ybuf, rowptr, col, b1_0, ubuf);
  k_fused<<<NB_TILE64, 256, 0, stream>>>(ubuf, w2_0, b2_0, w1_r, ybuf);
  for (int i = 0; i < 3; ++i) {
    k_agg<<<NB_WAVENODE, 256, 0, stream>>>(ybuf, rowptr, col, b1_r + i * H, ubuf);
    k_fused<<<NB_TILE64, 256, 0, stream>>>(ubuf, w2_r + i * H * H, b2_r + i * H,
                                           w1_r + (i + 1) * H * H, ybuf);
  }

  // ---- layer 4: agg, then GEMM2 + pool ----
  k_agg<<<NB_WAVENODE, 256, 0, stream>>>(ybuf, rowptr, col, b1_r + 3 * H, ubuf);
  k_last_pool<<<NB_TILE64, 256, 0, stream>>>(ubuf, w2_r + 3 * H * H, b2_r + 3 * H,
                                             batch, gbuf);

  // ---- readout ----
  k_readout<<<8, 64, 0, stream>>>(gbuf, mw1, mb1, mw2, mb2, out);
}